// Round 5
// baseline (7549.473 us; speedup 1.0000x reference)
//
#include <hip/hip_runtime.h>

// ---------------------------------------------------------------------------
// mLSTM epitope/antigen model, MI355X fp16-MFMA, round 11.
//
// R11 vs R10 (5.37 ms) / R8 (5.28 ms):
//  - 2-STEP FUSION with RELEASE-ONLY grid barriers. Evidence: R8 (LDS
//    B-share) and R10 (counted-vmcnt pipeline) both ~flat -> step kernels
//    are NOT datapath/latency bound. The ~20us/pair gap is the kernel
//    boundaries: every launch = agent release+acquire = wbl2 + L2 inv ->
//    ~39MB/step of weights re-stream L3->L2 at demand-paged rate + 2x
//    launch/drain. Fusing A+B+A+B into one kernel (306 -> 77 launches)
//    removes 3 of 4 boundaries per 2 steps.
//  - Barrier WITHOUT buffer_inv (R7's killer): arrive via
//    __hip_atomic_fetch_add(flag, 1, RELEASE, AGENT) -> lowers to
//    buffer_wbl2 (writeback only; L2 contents PRESERVED) + device atomic.
//    Spin via RELAXED agent loads (R7-proven). NO acquire anywhere.
//  - Staleness audit (why readers need no inv): within one kernel no XCD
//    re-reads lines it cached before they were rewritten:
//      mS ping-pong (mS0 step0, mS1 step1): each written-then-read once.
//      h  ping-pong: h_new untouched by any reader before B(t) writes it.
//      c: read+written only by the same block instance (own-L2 dirty hit).
//      weights/xe16/sel: read-only. L2 starts clean (launch inv).
//  - Work decode == R8 grids (incl. XCD-stable ct%8==colq%8==blockIdx&7);
//    inner pipelined bodies == R8 verbatim (proven 5.28 ms structure).
//    Grid = 256 blocks, 1/CU by LDS (64KB) -> co-resident -> no deadlock;
//    no early returns (all blocks hit all barriers).
// ---------------------------------------------------------------------------

typedef _Float16 f16;
typedef _Float16 half8 __attribute__((ext_vector_type(8)));
typedef float f32x4 __attribute__((ext_vector_type(4)));

#define H_    1900
#define HP    1920
#define NKA   60     // K-chunks for h/WmhS (1920/32)
#define NKB   61     // K-chunks for m/WhS (1952/32)
#define NKF   120    // K-chunks for fc1 (3840/32)
#define NR    512
#define TT    153
#define TE    25
#define EMB_  10
#define FCN   384
#define NBLK  256

__device__ __forceinline__ float sigm(float x) {
  float p = __expf(-fabsf(x));
  float r = 1.f / (1.f + p);
  return x >= 0.f ? r : 1.f - r;
}
__device__ __forceinline__ float tanh_(float x) {
  float p = __expf(-2.f * fabsf(x));
  float r = (1.f - p) / (1.f + p);
  return x >= 0.f ? r : -r;
}

// async global->LDS, 16B per lane; LDS dest is wave-uniform base + lane*16
__device__ __forceinline__ void gll16(const f16* g, f16* l) {
  __builtin_amdgcn_global_load_lds(
      (const __attribute__((address_space(1))) unsigned int*)g,
      (__attribute__((address_space(3))) unsigned int*)l, 16, 0, 0);
}

// Release-only grid barrier. fetch_add(RELEASE, AGENT) emits buffer_wbl2
// (writeback, NO invalidate -> L2-resident weights survive) before the
// device-scope atomic. Spin = relaxed agent loads (bypass L2; R7-proven
// no-deadlock). No acquire: reader freshness guaranteed by the staleness
// audit in the header comment.
__device__ __forceinline__ void gsync(int* flag) {
  asm volatile("s_waitcnt vmcnt(0)" ::: "memory");
  __syncthreads();
  if (threadIdx.x == 0) {
    __hip_atomic_fetch_add(flag, 1, __ATOMIC_RELEASE, __HIP_MEMORY_SCOPE_AGENT);
    while (__hip_atomic_load(flag, __ATOMIC_RELAXED, __HIP_MEMORY_SCOPE_AGENT) < NBLK) {
      __builtin_amdgcn_s_sleep(2);
    }
  }
  __syncthreads();
  asm volatile("" ::: "memory");
}

// ---------------- prep ----------------

__global__ void k_norms(const float* __restrict__ wh, const float* __restrict__ wx,
                        const float* __restrict__ wmh, const float* __restrict__ wmx,
                        const float* __restrict__ gh, const float* __restrict__ gx,
                        const float* __restrict__ gmh, const float* __restrict__ gmx,
                        float* __restrict__ inv_wh, float* __restrict__ inv_wx,
                        float* __restrict__ inv_wmh, float* __restrict__ inv_wmx) {
  int tid = blockIdx.x * 256 + threadIdx.x;
  if (tid < 7600) {
    float s = 0.f;
    for (int k = 0; k < H_; k++) { float v = wh[(size_t)k * 7600 + tid]; s += v * v; }
    inv_wh[tid] = gh[tid] * rsqrtf(fmaxf(s, 1e-12f));
  } else if (tid < 15200) {
    int n = tid - 7600; float s = 0.f;
    for (int e = 0; e < EMB_; e++) { float v = wx[(size_t)e * 7600 + n]; s += v * v; }
    inv_wx[n] = gx[n] * rsqrtf(fmaxf(s, 1e-12f));
  } else if (tid < 17100) {
    int n = tid - 15200; float s = 0.f;
    for (int k = 0; k < H_; k++) { float v = wmh[(size_t)k * H_ + n]; s += v * v; }
    inv_wmh[n] = gmh[n] * rsqrtf(fmaxf(s, 1e-12f));
  } else if (tid < 19000) {
    int n = tid - 17100; float s = 0.f;
    for (int e = 0; e < EMB_; e++) { float v = wmx[(size_t)e * H_ + n]; s += v * v; }
    inv_wmx[n] = gmx[n] * rsqrtf(fmaxf(s, 1e-12f));
  }
}

// WmhS fragment-swizzled: group (c,kb): element (n=16c+nl, k=32kb+kl)
__global__ void k_wmhS(const float* __restrict__ wmh, const float* __restrict__ inv,
                       f16* __restrict__ WmhS) {
  int i = blockIdx.x * 256 + threadIdx.x;
  if (i >= 1920 * 1920) return;
  int n = i % 1920, k = i / 1920;
  float v = (n < H_ && k < H_) ? wmh[(size_t)k * H_ + n] * inv[n] : 0.f;
  int c = n >> 4, nl = n & 15, kb = k >> 5, kl = k & 31;
  WmhS[(((size_t)c * NKA + kb) * 512) + (nl + 16 * (kl >> 3)) * 8 + (kl & 7)] = (f16)v;
}

// WhS fragment-swizzled, gate-grouped: group (q*4+g, kb); K-ext rows carry wx/b
__global__ void k_whS(const float* __restrict__ wh, const float* __restrict__ wx,
                      const float* __restrict__ bias,
                      const float* __restrict__ inv_wh, const float* __restrict__ inv_wx,
                      f16* __restrict__ WhS) {
  int i = blockIdx.x * 256 + threadIdx.x;
  if (i >= 7600 * 1952) return;
  int col = i % 7600, k = i / 7600;
  float v = 0.f;
  if (k < H_)                        v = wh[(size_t)k * 7600 + col] * inv_wh[col];
  else if (k >= HP && k < HP + EMB_) v = wx[(size_t)(k - HP) * 7600 + col] * inv_wx[col];
  else if (k == HP + EMB_)           v = bias[col];
  int g = col / H_, n = col % H_;
  int q = n >> 4, nl = n & 15, kb = k >> 5, kl = k & 31;
  WhS[(((size_t)(q * 4 + g) * NKB + kb) * 512) + (nl + 16 * (kl >> 3)) * 8 + (kl & 7)] = (f16)v;
}

__global__ void k_wmxT(const float* __restrict__ wmx, const float* __restrict__ inv_wmx,
                       f16* __restrict__ wmxT) {
  int i = blockIdx.x * 256 + threadIdx.x;
  if (i >= HP * 32) return;
  int n = i >> 5, k = i & 31;
  float v = (k < EMB_ && n < H_) ? wmx[(size_t)k * H_ + n] * inv_wmx[n] : 0.f;
  wmxT[i] = (f16)v;
}

__global__ void k_lens(const int* __restrict__ ex, const int* __restrict__ lx,
                       const int* __restrict__ rx, int* __restrict__ sel) {
  int s = threadIdx.x;
  int el = 0; for (int i = 0; i < 25; i++) el += (ex[s * 25 + i] != 26);
  int ll = 0; for (int i = 0; i < 64; i++) ll += (lx[s * 64 + i] != 26);
  int rl = 0; for (int i = 0; i < 64; i++) rl += (rx[s * 64 + i] != 26);
  ll = ll < 1 ? 1 : ll;  rl = rl < 1 ? 1 : rl;
  int tl = el + ll + rl;
  int ti = tl - 1; ti = ti < 0 ? 0 : (ti > 152 ? 152 : ti);
  int ei = el - 1; ei = ei < 0 ? 0 : (ei > 24 ? 24 : ei);
  sel[s] = ti; sel[256 + s] = ei;
}

__global__ void k_init(f16* __restrict__ h0, f16* __restrict__ h1,
                       float* __restrict__ c, int* __restrict__ flags) {
  int i = blockIdx.x * 256 + threadIdx.x;
  if (i < NR * HP) { h0[i] = (f16)0.f; h1[i] = (f16)0.f; c[i] = 0.f; }
  if (i < 256) flags[i] = 0;   // re-zeroed every graph replay
}

// xe16[t][row][32]: cols 0..9 = embed[token], col 10 = 1.0 (bias), rest 0
__global__ void k_xe16(const int* __restrict__ totx, const int* __restrict__ epix,
                       const float* __restrict__ embed, f16* __restrict__ xe16) {
  int i = blockIdx.x * blockDim.x + threadIdx.x;
  if (i >= TT * NR) return;
  int t = i / NR, r = i % NR;
  int tok = -1;
  if (r < 256) tok = totx[r * TT + t];
  else if (t < TE) tok = epix[(r - 256) * TE + t];
  f16* o = xe16 + (size_t)i * 32;
  #pragma unroll
  for (int e = 0; e < EMB_; e++) o[e] = (f16)(tok >= 0 ? embed[tok * EMB_ + e] : 0.f);
  o[10] = (f16)1.f;
  #pragma unroll
  for (int e = 11; e < 32; e++) o[e] = (f16)0.f;
}

// ---------------- fused 2-step recurrence ----------------
// Grid = 256 blocks x 256 threads. Per step: phase A (h@WmhS * x@wmxT -> mS),
// release-barrier, phase B (mS@WhS -> gates -> c, h). Items decoded so that
// ct%8 == colq%8 == blockIdx&7 (XCD-stable weight slices, as R8).

__global__ __launch_bounds__(256, 1)
void k_step2(const f16* __restrict__ WmhS, const f16* __restrict__ WhS,
             const f16* __restrict__ wmxT, const f16* __restrict__ xe16,
             f16* __restrict__ h0S, f16* __restrict__ h1S,
             f16* __restrict__ mS0, f16* __restrict__ mS1,
             float* __restrict__ cst, float* __restrict__ selH,
             const int* __restrict__ sel, int* __restrict__ flag3,
             int t0, int ns) {
  __shared__ __align__(16) f16 Bb[2][8][4][512];   // 64 KB
  const int lane = threadIdx.x & 63, wid = threadIdx.x >> 6;
  const int x = blockIdx.x & 7, m = blockIdx.x >> 3;   // m in [0,32)
  const int l16 = lane & 15, l4 = lane >> 4;
  const int q4 = l4, c16 = l16;
  int bar = 0;

#define STAGE_A(g, buf, n_) { _Pragma("unroll") for (int q_ = 0; q_ < 8; q_++) { \
    int p_ = wid * 8 + q_; \
    if (p_ < (n_) * 4) { int kbl_ = p_ >> 2, cb_ = p_ & 3; \
      gll16(BglobA + ((size_t)cb_ * NKA + (g) * 8 + kbl_) * 512, &Bb[buf][kbl_][cb_][0]); } } }
#define LOADA_A(g, buf, n_) { _Pragma("unroll") for (int kk_ = 0; kk_ < 8; kk_++) if (kk_ < (n_)) \
    ArA[buf][kk_] = *(const half8*)(AbaseA + (size_t)((g) * 8 + kk_) * 512); }
#define COMP_A(g, buf, n_) { _Pragma("unroll") for (int kk_ = 0; kk_ < 8; kk_++) if (kk_ < (n_)) { \
    half8 b0_ = *(const half8*)&Bb[buf][kk_][0][lane * 8]; \
    half8 b1_ = *(const half8*)&Bb[buf][kk_][1][lane * 8]; \
    half8 b2_ = *(const half8*)&Bb[buf][kk_][2][lane * 8]; \
    half8 b3_ = *(const half8*)&Bb[buf][kk_][3][lane * 8]; \
    accA[0] = __builtin_amdgcn_mfma_f32_16x16x32_f16(ArA[buf][kk_], b0_, accA[0], 0, 0, 0); \
    accA[1] = __builtin_amdgcn_mfma_f32_16x16x32_f16(ArA[buf][kk_], b1_, accA[1], 0, 0, 0); \
    accA[2] = __builtin_amdgcn_mfma_f32_16x16x32_f16(ArA[buf][kk_], b2_, accA[2], 0, 0, 0); \
    accA[3] = __builtin_amdgcn_mfma_f32_16x16x32_f16(ArA[buf][kk_], b3_, accA[3], 0, 0, 0); } }

#define STAGE_B(g, buf, n_) { _Pragma("unroll") for (int q_ = 0; q_ < 8; q_++) { \
    int p_ = wid * 8 + q_; \
    if (p_ < (n_) * 4) { int kbl_ = p_ >> 2, gg_ = p_ & 3; \
      gll16(BglobB + ((size_t)gg_ * NKB + (g) * 8 + kbl_) * 512, &Bb[buf][kbl_][gg_][0]); } } }
#define LOADA_B(g, buf, n_) { _Pragma("unroll") for (int kk_ = 0; kk_ < 8; kk_++) if (kk_ < (n_)) { \
    ArB[buf][kk_][0] = *(const half8*)(AbaseB + (size_t)((g) * 8 + kk_) * 512); \
    ArB[buf][kk_][1] = *(const half8*)(AbaseB + ((size_t)NKB + (g) * 8 + kk_) * 512); } }
#define COMP_B(g, buf, n_) { _Pragma("unroll") for (int kk_ = 0; kk_ < 8; kk_++) if (kk_ < (n_)) { \
    half8 b0_ = *(const half8*)&Bb[buf][kk_][0][lane * 8]; \
    half8 b1_ = *(const half8*)&Bb[buf][kk_][1][lane * 8]; \
    half8 b2_ = *(const half8*)&Bb[buf][kk_][2][lane * 8]; \
    half8 b3_ = *(const half8*)&Bb[buf][kk_][3][lane * 8]; \
    _Pragma("unroll") for (int rf_ = 0; rf_ < 2; rf_++) { \
      accB[rf_][0] = __builtin_amdgcn_mfma_f32_16x16x32_f16(ArB[buf][kk_][rf_], b0_, accB[rf_][0], 0, 0, 0); \
      accB[rf_][1] = __builtin_amdgcn_mfma_f32_16x16x32_f16(ArB[buf][kk_][rf_], b1_, accB[rf_][1], 0, 0, 0); \
      accB[rf_][2] = __builtin_amdgcn_mfma_f32_16x16x32_f16(ArB[buf][kk_][rf_], b2_, accB[rf_][2], 0, 0, 0); \
      accB[rf_][3] = __builtin_amdgcn_mfma_f32_16x16x32_f16(ArB[buf][kk_][rf_], b3_, accB[rf_][3], 0, 0, 0); } } }

  for (int s = 0; s < ns; s++) {
    const int t = t0 + s;
    const int Mt = (t < TE) ? NR : 256;
    const f16* hS = (t & 1) ? h1S : h0S;
    f16* ho = (t & 1) ? h0S : h1S;
    f16* mS = s ? mS1 : mS0;
    const f16* xet = xe16 + (size_t)t * NR * 32;
    const int rgcA = Mt / 64, rgcB = Mt / 128;

    // ---------------- phase A ----------------
    {
      const int nct = (x < 6) ? 4 : 3;
      const int itemsA = nct * rgcA;          // <= 32
      for (int it = m; it < itemsA; it += 32) {
        const int ct = (it / rgcA) * 8 + x;   // ct%8 == x
        const int rg = it % rgcA;
        const int rtile = rg * 4 + wid;
        const int r0 = rtile * 16;

        const f16* AbaseA = hS   + (size_t)rtile * NKA * 512 + lane * 8;
        const f16* BglobA = WmhS + (size_t)(ct * 4) * NKA * 512 + lane * 8;

        // xm = xe16 @ wmxT (once per wave)
        f32x4 xm[4];
        {
          half8 xa = *(const half8*)(xet + (size_t)(r0 + l16) * 32 + l4 * 8);
          #pragma unroll
          for (int cb = 0; cb < 4; cb++) {
            half8 xb = *(const half8*)(wmxT + (size_t)(ct * 64 + cb * 16 + l16) * 32 + l4 * 8);
            f32x4 z = {0.f, 0.f, 0.f, 0.f};
            xm[cb] = __builtin_amdgcn_mfma_f32_16x16x32_f16(xa, xb, z, 0, 0, 0);
          }
        }

        half8 ArA[2][8];
        f32x4 accA[4];
        #pragma unroll
        for (int cb = 0; cb < 4; cb++) { f32x4 z = {0.f, 0.f, 0.f, 0.f}; accA[cb] = z; }

        LOADA_A(0, 0, 8); STAGE_A(0, 0, 8);
        __syncthreads();
        #pragma unroll
        for (int g = 0; g < 8; g++) {
          const int nn = (g == 7) ? 4 : 8;
          if (g < 7) {
            const int nn1 = (g == 6) ? 4 : 8;
            STAGE_A(g + 1, (g + 1) & 1, nn1); LOADA_A(g + 1, (g + 1) & 1, nn1);
          }
          COMP_A(g, g & 1, nn);
          __syncthreads();
        }

        // epilogue: m = hm * xm, written in phase-B's A-fragment order
        #pragma unroll
        for (int cb = 0; cb < 4; cb++) {
          int kb = ct * 2 + (cb >> 1);
          int klane = (cb & 1) * 16 + c16;
          int lf = (klane >> 3) * 16;
          int sub = c16 & 7;
          f16* dst = mS + ((size_t)rtile * NKB + kb) * 512 + sub;
          #pragma unroll
          for (int q = 0; q < 4; q++) {
            int rl = q4 * 4 + q;
            dst[(rl + lf) * 8] = (f16)(accA[cb][q] * xm[cb][q]);
          }
        }
        if (ct == 0) {  // K-extension chunk 60 = xe16 row (contiguous copy)
          f16* dst = mS + ((size_t)rtile * NKB + 60) * 512 + lane * 8;
          *(half8*)dst = *(const half8*)(xet + (size_t)(r0 + l16) * 32 + l4 * 8);
        }
      }
    }

    gsync(flag3 + bar); bar++;     // mS visible (release/wbl2, no inv)

    // ---------------- phase B ----------------
    {
      const int ncq = (x == 7) ? 14 : 15;
      const int itemsB = ncq * rgcB;
      for (int it = m; it < itemsB; it += 32) {
        const int colq = (it / rgcB) * 8 + x;   // colq%8 == x, <= 118
        const int rg = it % rgcB;
        const int rt0 = (rg * 4 + wid) * 2;
        const int r0 = rt0 * 16;

        const f16* AbaseB = mS  + (size_t)rt0 * NKB * 512 + lane * 8;
        const f16* BglobB = WhS + (size_t)(colq * 4) * NKB * 512 + lane * 8;

        half8 ArB[2][8][2];
        f32x4 accB[2][4];
        #pragma unroll
        for (int a = 0; a < 2; a++)
          #pragma unroll
          for (int b = 0; b < 4; b++) { f32x4 z = {0.f, 0.f, 0.f, 0.f}; accB[a][b] = z; }

        LOADA_B(0, 0, 8); STAGE_B(0, 0, 8);
        __syncthreads();
        #pragma unroll
        for (int g = 0; g < 8; g++) {
          const int nn = (g == 7) ? 5 : 8;
          if (g < 7) {
            const int nn1 = (g == 6) ? 5 : 8;
            STAGE_B(g + 1, (g + 1) & 1, nn1); LOADA_B(g + 1, (g + 1) & 1, nn1);
          }
          COMP_B(g, g & 1, nn);
          __syncthreads();
        }

        const int j = colq * 16 + c16;
        const bool valid = j < H_;
        const int kbh = colq >> 1;
        const int lfh = ((((colq & 1) * 16 + c16) >> 3)) * 16;
        const int subh = c16 & 7;
        #pragma unroll
        for (int rf = 0; rf < 2; rf++) {
          f16* hdst = ho + ((size_t)(rt0 + rf) * NKA + kbh) * 512 + subh;
          #pragma unroll
          for (int q = 0; q < 4; q++) {
            int rl = q4 * 4 + q;
            int row = r0 + rf * 16 + rl;
            if (valid) {
              size_t idx = (size_t)row * HP + j;
              float cold = cst[idx];
              float iz = accB[rf][0][q], fz = accB[rf][1][q];
              float oz = accB[rf][2][q], uz = accB[rf][3][q];
              float cn = sigm(fz) * cold + sigm(iz) * tanh_(uz);
              float hv = sigm(oz) * tanh_(cn);
              cst[idx] = cn;
              hdst[(rl + lfh) * 8] = (f16)hv;
              if (t == sel[row]) selH[idx] = hv;
            }
          }
        }
      }
    }

    if (s + 1 < ns) { gsync(flag3 + bar); bar++; }   // h visible for A(t+1)
  }
#undef STAGE_A
#undef LOADA_A
#undef COMP_A
#undef STAGE_B
#undef LOADA_B
#undef COMP_B
}

// ---------------- classifier ----------------

__global__ void k_xqS(const float* __restrict__ selH, const float* __restrict__ g1,
                      const float* __restrict__ be1, const float* __restrict__ mu1,
                      const float* __restrict__ var1, f16* __restrict__ xqS) {
  int i = blockIdx.x * 256 + threadIdx.x;
  if (i >= 256 * 3840) return;
  int k = i % 3840, s = i / 3840;
  float v = 0.f; bool have = false;
  if (k < H_)            { v = selH[(size_t)s * HP + k]; have = true; }
  else if (k < 2 * H_)   { v = selH[(size_t)(256 + s) * HP + (k - H_)]; have = true; }
  float q = 0.f;
  if (have) {
    float lr = v < 0.f ? 0.3f * v : v;
    q = (lr - mu1[k]) * rsqrtf(var1[k] + 1e-3f) * g1[k] + be1[k];
  }
  int rtile = s >> 4, sl = s & 15, kb = k >> 5, kl = k & 31;
  xqS[(((size_t)rtile * NKF + kb) * 512) + (sl + 16 * (kl >> 3)) * 8 + (kl & 7)] = (f16)q;
}

__global__ void k_w1S(const float* __restrict__ W1, f16* __restrict__ W1S) {
  int i = blockIdx.x * 256 + threadIdx.x;
  if (i >= 384 * 3840) return;
  int col = i % 384, k = i / 384;
  float v = (col < 380 && k < 2 * H_) ? W1[(size_t)k * 380 + col] : 0.f;
  int cg = col >> 4, nl = col & 15, kb = k >> 5, kl = k & 31;
  W1S[(((size_t)cg * NKF + kb) * 512) + (nl + 16 * (kl >> 3)) * 8 + (kl & 7)] = (f16)v;
}

// fc1: wave = 16 rows x 64 cols, K=3840 (120 chunks), branch-free pipeline
__global__ __launch_bounds__(256)
void k_fc1(const f16* __restrict__ xqS, const f16* __restrict__ W1S,
           const float* __restrict__ b1, float* __restrict__ z1) {
  const int lane = threadIdx.x & 63, wid = threadIdx.x >> 6;
  const int ct = blockIdx.x % 6, rg = blockIdx.x / 6;
  const int rtile = rg * 4 + wid;
  const int r0 = rtile * 16;

  const f16* Abase = xqS + (size_t)rtile * NKF * 512 + lane * 8;
  const f16* Bbase = W1S + (size_t)(ct * 4) * NKF * 512 + lane * 8;

  half8 fa0, fa1, fa2, fa3;
  half8 fb0[4], fb1[4], fb2[4], fb3[4];
  f32x4 acc[4];
  #pragma unroll
  for (int cb = 0; cb < 4; cb++) { f32x4 z = {0.f, 0.f, 0.f, 0.f}; acc[cb] = z; }

#define LDA_F(d, kb)  d = *(const half8*)(Abase + (size_t)(kb) * 512)
#define LDB_F(d, kb)  { _Pragma("unroll") for (int cb = 0; cb < 4; cb++) \
    d[cb] = *(const half8*)(Bbase + ((size_t)cb * NKF + (kb)) * 512); }
#define MMA_F(fa, fb) { _Pragma("unroll") for (int cb = 0; cb < 4; cb++) \
    acc[cb] = __builtin_amdgcn_mfma_f32_16x16x32_f16(fa, fb[cb], acc[cb], 0, 0, 0); }

  LDA_F(fa0, 0); LDB_F(fb0, 0);
  LDA_F(fa1, 1); LDB_F(fb1, 1);
  LDA_F(fa2, 2); LDB_F(fb2, 2);
  for (int base = 0; base < 116; base += 4) {
    LDA_F(fa3, base + 3); LDB_F(fb3, base + 3);
    MMA_F(fa0, fb0);
    LDA_F(fa0, base + 4); LDB_F(fb0, base + 4);
    MMA_F(fa1, fb1);
    LDA_F(fa1, base + 5); LDB_F(fb1, base + 5);
    MMA_F(fa2, fb2);
    LDA_F(fa2, base + 6); LDB_F(fb2, base + 6);
    MMA_F(fa3, fb3);
  }
  LDA_F(fa3, 119); LDB_F(fb3, 119);
  MMA_F(fa0, fb0);   // 116
  MMA_F(fa1, fb1);   // 117
  MMA_F(fa2, fb2);   // 118
  MMA_F(fa3, fb3);   // 119
#undef LDA_F
#undef LDB_F
#undef MMA_F

  const int q4 = lane >> 4, c16 = lane & 15;
  #pragma unroll
  for (int cb = 0; cb < 4; cb++)
    #pragma unroll
    for (int q = 0; q < 4; q++) {
      int row = r0 + q4 * 4 + q;
      int col = ct * 64 + cb * 16 + c16;
      float bias = (col < 380) ? b1[col] : 0.f;
      z1[(size_t)row * FCN + col] = acc[cb][q] + bias;
    }
}

__global__ void k_fc2(const float* __restrict__ z1, const float* __restrict__ g2,
                      const float* __restrict__ be2, const float* __restrict__ mu2,
                      const float* __restrict__ var2, const float* __restrict__ W2,
                      const float* __restrict__ b2, float* __restrict__ out) {
  int s = threadIdx.x;
  float a = 0.f;
  for (int jj = 0; jj < 380; jj++) {
    float v = z1[(size_t)s * FCN + jj];
    float lr = v < 0.f ? 0.3f * v : v;
    float q = (lr - mu2[jj]) * rsqrtf(var2[jj] + 1e-3f) * g2[jj] + be2[jj];
    a += q * W2[jj];
  }
  out[s] = a + b2[0];
}

// ---------------- host ----------------

extern "C" void kernel_launch(void* const* d_in, const int* in_sizes, int n_in,
                              void* d_out, int out_size, void* d_ws, size_t ws_size,
                              hipStream_t stream) {
  const int*   epix  = (const int*)d_in[0];
  const int*   lx    = (const int*)d_in[1];
  const int*   rx    = (const int*)d_in[2];
  const int*   totx  = (const int*)d_in[3];
  const float* embed = (const float*)d_in[4];
  const float* wx    = (const float*)d_in[5];
  const float* wh    = (const float*)d_in[6];
  const float* wmx   = (const float*)d_in[7];
  const float* wmh   = (const float*)d_in[8];
  const float* bb    = (const float*)d_in[9];
  const float* gx    = (const float*)d_in[10];
  const float* gh    = (const float*)d_in[11];
  const float* gmx   = (const float*)d_in[12];
  const float* gmh   = (const float*)d_in[13];
  const float* bn1g  = (const float*)d_in[14];
  const float* bn1b  = (const float*)d_in[15];
  const float* bn1m  = (const float*)d_in[16];
  const float* bn1v  = (const float*)d_in[17];
  const float* W1    = (const float*)d_in[18];
  const float* b1    = (const float*)d_in[19];
  const float* bn2g  = (const float*)d_in[20];
  const float* bn2b  = (const float*)d_in[21];
  const float* bn2m  = (const float*)d_in[22];
  const float* bn2v  = (const float*)d_in[23];
  const float* W2    = (const float*)d_in[24];
  const float* b2v   = (const float*)d_in[25];

  char* base = (char*)d_ws;
  size_t off = 0;
  auto alloc = [&](size_t n) { char* p = base + off; off = (off + n + 255) & ~(size_t)255; return p; };

  f16*   WmhS   = (f16*)  alloc((size_t)120 * NKA * 512 * 2);
  f16*   WhS    = (f16*)  alloc((size_t)119 * 4 * NKB * 512 * 2);
  f16*   wmxT   = (f16*)  alloc((size_t)HP * 32 * 2);
  f16*   xe16   = (f16*)  alloc((size_t)TT * NR * 32 * 2);
  f16*   h0S    = (f16*)  alloc((size_t)32 * NKA * 512 * 2);
  f16*   h1S    = (f16*)  alloc((size_t)32 * NKA * 512 * 2);
  f16*   mS0    = (f16*)  alloc((size_t)32 * NKB * 512 * 2);
  f16*   mS1    = (f16*)  alloc((size_t)32 * NKB * 512 * 2);
  float* cst    = (float*)alloc((size_t)NR * HP * 4);
  float* selH   = (float*)alloc((size_t)NR * HP * 4);
  int*   sel    = (int*)  alloc((size_t)NR * 4);
  float* inv_wh = (float*)alloc(7600 * 4);
  float* inv_wx = (float*)alloc(7600 * 4);
  float* inv_wmh= (float*)alloc(1900 * 4);
  float* inv_wmx= (float*)alloc(1900 * 4);
  f16*   xqS    = (f16*)  alloc((size_t)16 * NKF * 512 * 2);
  f16*   W1S    = (f16*)  alloc((size_t)24 * NKF * 512 * 2);
  float* z1     = (float*)alloc((size_t)256 * FCN * 4);
  int*   flags  = (int*)  alloc(256 * 4);
  (void)in_sizes; (void)n_in; (void)out_size; (void)ws_size;

  hipLaunchKernelGGL(k_norms, dim3(75), dim3(256), 0, stream,
                     wh, wx, wmh, wmx, gh, gx, gmh, gmx, inv_wh, inv_wx, inv_wmh, inv_wmx);
  hipLaunchKernelGGL(k_wmhS, dim3((1920 * 1920 + 255) / 256), dim3(256), 0, stream,
                     wmh, inv_wmh, WmhS);
  hipLaunchKernelGGL(k_whS, dim3((7600 * 1952 + 255) / 256), dim3(256), 0, stream,
                     wh, wx, bb, inv_wh, inv_wx, WhS);
  hipLaunchKernelGGL(k_wmxT, dim3((HP * 32 + 255) / 256), dim3(256), 0, stream,
                     wmx, inv_wmx, wmxT);
  hipLaunchKernelGGL(k_lens, dim3(1), dim3(256), 0, stream, epix, lx, rx, sel);
  hipLaunchKernelGGL(k_init, dim3((NR * HP + 255) / 256), dim3(256), 0, stream,
                     h0S, h1S, cst, flags);
  hipLaunchKernelGGL(k_xe16, dim3((TT * NR + 255) / 256), dim3(256), 0, stream,
                     totx, epix, embed, xe16);

  // recurrence: 2 steps per launch (153 = 76 pairs + 1 single)
  for (int t0 = 0; t0 < TT; t0 += 2) {
    int ns = (t0 + 1 < TT) ? 2 : 1;
    hipLaunchKernelGGL(k_step2, dim3(NBLK), dim3(256), 0, stream,
                       WmhS, WhS, wmxT, xe16, h0S, h1S, mS0, mS1,
                       cst, selH, sel, flags + (t0 / 2) * 3, t0, ns);
  }

  hipLaunchKernelGGL(k_xqS, dim3((256 * 3840 + 255) / 256), dim3(256), 0, stream,
                     selH, bn1g, bn1b, bn1m, bn1v, xqS);
  hipLaunchKernelGGL(k_w1S, dim3((384 * 3840 + 255) / 256), dim3(256), 0, stream, W1, W1S);
  hipLaunchKernelGGL(k_fc1, dim3(24), dim3(256), 0, stream, xqS, W1S, b1, z1);
  hipLaunchKernelGGL(k_fc2, dim3(1), dim3(256), 0, stream,
                     z1, bn2g, bn2b, bn2m, bn2v, W2, b2v, (float*)d_out);
}

// Round 6
// 4693.629 us; speedup vs baseline: 1.6085x; 1.6085x over previous
//
#include <hip/hip_runtime.h>

// ---------------------------------------------------------------------------
// mLSTM epitope/antigen model, MI355X fp16-MFMA, round 12.
//
// R12 vs R8 (5.28 ms; R10/R11 experiments flat/worse and reverted):
//  - MODEL (from R11 counters): recurrence is weight-fill bound. 42 MB/step
//    mandatory stream (per-XCD slice 4.6 MB > 4 MB L2 -> LRU cycling, no
//    cross-step residency possible) at ~1.25 TB/s effective = 33.6 us/step.
//    Fusion lowers the rate (750 GB/s, barrier dead time + wbl2 storms) ->
//    multi-kernel skeleton is right; improve RATE via concurrency.
//  - stepA CT-HALF SPLIT: was 120 active blocks (half the chip idle);
//    now each block does 2 cb (32 cols) -> 240/480 blocks, LDS 32 KB,
//    launch_bounds(256,2). Same bytes, 2x the miss-issue concurrency.
//  - stepB unchanged (R8 body, 240 blocks, chip-covering).
//  - k_norms split into 4-way K-partials + finalize (was 30 blocks with
//    serial 1900-iter loops; latency-bound fixed cost).
// ---------------------------------------------------------------------------

typedef _Float16 f16;
typedef _Float16 half8 __attribute__((ext_vector_type(8)));
typedef float f32x4 __attribute__((ext_vector_type(4)));

#define H_    1900
#define HP    1920
#define NKA   60     // K-chunks for h/WmhS (1920/32)
#define NKB   61     // K-chunks for m/WhS (1952/32)
#define NKF   120    // K-chunks for fc1 (3840/32)
#define NR    512
#define TT    153
#define TE    25
#define EMB_  10
#define FCN   384

__device__ __forceinline__ float sigm(float x) {
  float p = __expf(-fabsf(x));
  float r = 1.f / (1.f + p);
  return x >= 0.f ? r : 1.f - r;
}
__device__ __forceinline__ float tanh_(float x) {
  float p = __expf(-2.f * fabsf(x));
  float r = (1.f - p) / (1.f + p);
  return x >= 0.f ? r : -r;
}

// async global->LDS, 16B per lane; LDS dest is wave-uniform base + lane*16
__device__ __forceinline__ void gll16(const f16* g, f16* l) {
  __builtin_amdgcn_global_load_lds(
      (const __attribute__((address_space(1))) unsigned int*)g,
      (__attribute__((address_space(3))) unsigned int*)l, 16, 0, 0);
}

// ---------------- prep ----------------

// 4-way K-split partial sums-of-squares (wh: K=1900=4x475; wx/wmx: seg 0 only)
__global__ void k_norms_p(const float* __restrict__ wh, const float* __restrict__ wx,
                          const float* __restrict__ wmh, const float* __restrict__ wmx,
                          float* __restrict__ part) {
  int seg = blockIdx.x & 3;
  int tid = (blockIdx.x >> 2) * 256 + threadIdx.x;   // 0..19199
  float s = 0.f;
  if (tid < 7600) {
    int k0 = seg * 475;
    for (int k = k0; k < k0 + 475; k++) { float v = wh[(size_t)k * 7600 + tid]; s += v * v; }
  } else if (tid < 15200) {
    if (seg == 0) {
      int n = tid - 7600;
      for (int e = 0; e < EMB_; e++) { float v = wx[(size_t)e * 7600 + n]; s += v * v; }
    }
  } else if (tid < 17100) {
    int n = tid - 15200; int k0 = seg * 475;
    for (int k = k0; k < k0 + 475; k++) { float v = wmh[(size_t)k * H_ + n]; s += v * v; }
  } else if (tid < 19000) {
    if (seg == 0) {
      int n = tid - 17100;
      for (int e = 0; e < EMB_; e++) { float v = wmx[(size_t)e * H_ + n]; s += v * v; }
    }
  }
  if (tid < 19000) part[(size_t)seg * 19000 + tid] = s;
}

__global__ void k_norms_f(const float* __restrict__ part,
                          const float* __restrict__ gh, const float* __restrict__ gx,
                          const float* __restrict__ gmh, const float* __restrict__ gmx,
                          float* __restrict__ inv_wh, float* __restrict__ inv_wx,
                          float* __restrict__ inv_wmh, float* __restrict__ inv_wmx) {
  int tid = blockIdx.x * 256 + threadIdx.x;
  if (tid >= 19000) return;
  float s = part[tid] + part[19000 + tid] + part[38000 + tid] + part[57000 + tid];
  float r = rsqrtf(fmaxf(s, 1e-12f));
  if (tid < 7600)        inv_wh[tid] = gh[tid] * r;
  else if (tid < 15200)  { int n = tid - 7600;  inv_wx[n]  = gx[n]  * r; }
  else if (tid < 17100)  { int n = tid - 15200; inv_wmh[n] = gmh[n] * r; }
  else                   { int n = tid - 17100; inv_wmx[n] = gmx[n] * r; }
}

// WmhS fragment-swizzled: group (c,kb): element (n=16c+nl, k=32kb+kl)
__global__ void k_wmhS(const float* __restrict__ wmh, const float* __restrict__ inv,
                       f16* __restrict__ WmhS) {
  int i = blockIdx.x * 256 + threadIdx.x;
  if (i >= 1920 * 1920) return;
  int n = i % 1920, k = i / 1920;
  float v = (n < H_ && k < H_) ? wmh[(size_t)k * H_ + n] * inv[n] : 0.f;
  int c = n >> 4, nl = n & 15, kb = k >> 5, kl = k & 31;
  WmhS[(((size_t)c * NKA + kb) * 512) + (nl + 16 * (kl >> 3)) * 8 + (kl & 7)] = (f16)v;
}

// WhS fragment-swizzled, gate-grouped: group (q*4+g, kb); K-ext rows carry wx/b
__global__ void k_whS(const float* __restrict__ wh, const float* __restrict__ wx,
                      const float* __restrict__ bias,
                      const float* __restrict__ inv_wh, const float* __restrict__ inv_wx,
                      f16* __restrict__ WhS) {
  int i = blockIdx.x * 256 + threadIdx.x;
  if (i >= 7600 * 1952) return;
  int col = i % 7600, k = i / 7600;
  float v = 0.f;
  if (k < H_)                        v = wh[(size_t)k * 7600 + col] * inv_wh[col];
  else if (k >= HP && k < HP + EMB_) v = wx[(size_t)(k - HP) * 7600 + col] * inv_wx[col];
  else if (k == HP + EMB_)           v = bias[col];
  int g = col / H_, n = col % H_;
  int q = n >> 4, nl = n & 15, kb = k >> 5, kl = k & 31;
  WhS[(((size_t)(q * 4 + g) * NKB + kb) * 512) + (nl + 16 * (kl >> 3)) * 8 + (kl & 7)] = (f16)v;
}

__global__ void k_wmxT(const float* __restrict__ wmx, const float* __restrict__ inv_wmx,
                       f16* __restrict__ wmxT) {
  int i = blockIdx.x * 256 + threadIdx.x;
  if (i >= HP * 32) return;
  int n = i >> 5, k = i & 31;
  float v = (k < EMB_ && n < H_) ? wmx[(size_t)k * H_ + n] * inv_wmx[n] : 0.f;
  wmxT[i] = (f16)v;
}

__global__ void k_lens(const int* __restrict__ ex, const int* __restrict__ lx,
                       const int* __restrict__ rx, int* __restrict__ sel) {
  int s = threadIdx.x;
  int el = 0; for (int i = 0; i < 25; i++) el += (ex[s * 25 + i] != 26);
  int ll = 0; for (int i = 0; i < 64; i++) ll += (lx[s * 64 + i] != 26);
  int rl = 0; for (int i = 0; i < 64; i++) rl += (rx[s * 64 + i] != 26);
  ll = ll < 1 ? 1 : ll;  rl = rl < 1 ? 1 : rl;
  int tl = el + ll + rl;
  int ti = tl - 1; ti = ti < 0 ? 0 : (ti > 152 ? 152 : ti);
  int ei = el - 1; ei = ei < 0 ? 0 : (ei > 24 ? 24 : ei);
  sel[s] = ti; sel[256 + s] = ei;
}

__global__ void k_init(f16* __restrict__ h0, f16* __restrict__ h1, float* __restrict__ c) {
  int i = blockIdx.x * 256 + threadIdx.x;
  if (i < NR * HP) { h0[i] = (f16)0.f; h1[i] = (f16)0.f; c[i] = 0.f; }
}

// xe16[t][row][32]: cols 0..9 = embed[token], col 10 = 1.0 (bias), rest 0
__global__ void k_xe16(const int* __restrict__ totx, const int* __restrict__ epix,
                       const float* __restrict__ embed, f16* __restrict__ xe16) {
  int i = blockIdx.x * blockDim.x + threadIdx.x;
  if (i >= TT * NR) return;
  int t = i / NR, r = i % NR;
  int tok = -1;
  if (r < 256) tok = totx[r * TT + t];
  else if (t < TE) tok = epix[(r - 256) * TE + t];
  f16* o = xe16 + (size_t)i * 32;
  #pragma unroll
  for (int e = 0; e < EMB_; e++) o[e] = (f16)(tok >= 0 ? embed[tok * EMB_ + e] : 0.f);
  o[10] = (f16)1.f;
  #pragma unroll
  for (int e = 11; e < 32; e++) o[e] = (f16)0.f;
}

// ---------------- recurrence ----------------

// Phase A: block = (ct, cbh, rg); 4 waves x 16 rows x 32 cols (2 cb).
// B (WmhS half-slice) staged in LDS (32 KB, double-buffered), A in regs
// one group ahead. 2x the blocks of R8 -> full-chip fill concurrency.
__global__ __launch_bounds__(256, 2)
void k_stepA(const f16* __restrict__ hS, const f16* __restrict__ WmhS,
             const f16* __restrict__ xe16_t, const f16* __restrict__ wmxT,
             f16* __restrict__ mS, int rgc) {
  __shared__ __align__(16) f16 Bb[2][8][2][512];   // 32 KB
  const int lane = threadIdx.x & 63, wid = threadIdx.x >> 6;
  const int bi = blockIdx.x;
  const int x = bi & 7, mm = bi >> 3;
  const int rg = mm % rgc, rem = mm / rgc;
  const int cbh = rem & 1, chi = rem >> 1;
  const int ct = chi * 8 + x;                      // ct%8 == x (XCD-stable)
  if (ct >= 30) return;
  const int rtile = rg * 4 + wid;
  const int r0 = rtile * 16;
  const int l16 = lane & 15, l4 = lane >> 4;

  const f16* Abase = hS   + (size_t)rtile * NKA * 512 + lane * 8;
  const f16* Bglob = WmhS + (size_t)(ct * 4 + cbh * 2) * NKA * 512 + lane * 8;

  // xm = xe16 @ wmxT (once per wave, this block's 2 column-16-groups)
  f32x4 xm[2];
  {
    half8 xa = *(const half8*)(xe16_t + (size_t)(r0 + l16) * 32 + l4 * 8);
    #pragma unroll
    for (int cb = 0; cb < 2; cb++) {
      half8 xb = *(const half8*)(wmxT + (size_t)(ct * 64 + (cbh * 2 + cb) * 16 + l16) * 32 + l4 * 8);
      f32x4 z = {0.f, 0.f, 0.f, 0.f};
      xm[cb] = __builtin_amdgcn_mfma_f32_16x16x32_f16(xa, xb, z, 0, 0, 0);
    }
  }

  half8 Areg[2][8];
  f32x4 acc[2];
  #pragma unroll
  for (int cb = 0; cb < 2; cb++) { f32x4 z = {0.f, 0.f, 0.f, 0.f}; acc[cb] = z; }

  // groups: 7 full (8 chunks) + tail (4 chunks) = 60.
  // stage group g: n*2 fragments, n/2 per wave (n=8 -> 4/wave; n=4 -> 2/wave)
#define STAGE_A(g, buf, n_) { _Pragma("unroll") for (int q_ = 0; q_ < ((n_) >> 1); q_++) { \
    int p_ = wid * ((n_) >> 1) + q_; int kbl_ = p_ >> 1, cb_ = p_ & 1; \
    gll16(Bglob + ((size_t)cb_ * NKA + (g) * 8 + kbl_) * 512, &Bb[buf][kbl_][cb_][0]); } }
#define LOADA_A(g, buf, n_) { _Pragma("unroll") for (int kk_ = 0; kk_ < 8; kk_++) if (kk_ < (n_)) \
    Areg[buf][kk_] = *(const half8*)(Abase + (size_t)((g) * 8 + kk_) * 512); }
#define COMP_A(g, buf, n_) { _Pragma("unroll") for (int kk_ = 0; kk_ < 8; kk_++) if (kk_ < (n_)) { \
    half8 b0_ = *(const half8*)&Bb[buf][kk_][0][lane * 8]; \
    half8 b1_ = *(const half8*)&Bb[buf][kk_][1][lane * 8]; \
    acc[0] = __builtin_amdgcn_mfma_f32_16x16x32_f16(Areg[buf][kk_], b0_, acc[0], 0, 0, 0); \
    acc[1] = __builtin_amdgcn_mfma_f32_16x16x32_f16(Areg[buf][kk_], b1_, acc[1], 0, 0, 0); } }

  LOADA_A(0, 0, 8); STAGE_A(0, 0, 8);
  __syncthreads();
  #pragma unroll
  for (int g = 0; g < 8; g++) {
    const int nn = (g == 7) ? 4 : 8;
    if (g < 7) {
      const int nn1 = (g == 6) ? 4 : 8;
      STAGE_A(g + 1, (g + 1) & 1, nn1); LOADA_A(g + 1, (g + 1) & 1, nn1);
    }
    COMP_A(g, g & 1, nn);
    __syncthreads();
  }
#undef STAGE_A
#undef LOADA_A
#undef COMP_A

  // epilogue: m = hm * xm, written in stepB's A-fragment order.
  // global cb = cbh*2+cb2: kb = ct*2 + cbh, klane = cb2*16 + c16
  const int q4 = lane >> 4, c16 = lane & 15;
  const int kb = ct * 2 + cbh;
  #pragma unroll
  for (int cb = 0; cb < 2; cb++) {
    int klane = cb * 16 + c16;
    int lf = (klane >> 3) * 16;
    int sub = c16 & 7;
    f16* dst = mS + ((size_t)rtile * NKB + kb) * 512 + sub;
    #pragma unroll
    for (int q = 0; q < 4; q++) {
      int rl = q4 * 4 + q;
      dst[(rl + lf) * 8] = (f16)(acc[cb][q] * xm[cb][q]);
    }
  }
  if (ct == 0 && cbh == 0) {  // K-extension chunk 60 = xe16 row (contiguous copy)
    f16* dst = mS + ((size_t)rtile * NKB + 60) * 512 + lane * 8;
    *(half8*)dst = *(const half8*)(xe16_t + (size_t)(r0 + l16) * 32 + l4 * 8);
  }
}

// Phase B: block = (colq, rg); 4 waves x 32 rows; B (WhS gate-quad,
// block-uniform) staged in LDS; A (mS rows) per-wave registers. (R8 body.)
__global__ __launch_bounds__(256, 1)
void k_stepB(const f16* __restrict__ mS, const f16* __restrict__ WhS,
             float* __restrict__ c, f16* __restrict__ houtS,
             float* __restrict__ selH, const int* __restrict__ sel, int t, int rgc) {
  __shared__ __align__(16) f16 Bb[2][8][4][512];   // 64 KB
  const int lane = threadIdx.x & 63, wid = threadIdx.x >> 6;
  const int bi = blockIdx.x;
  const int x = bi & 7, mm = bi >> 3;
  const int rg = mm % rgc, chi = mm / rgc;
  const int colq = chi * 8 + x;                    // colq%8 == x (XCD-stable)
  if (colq >= 119) return;
  const int rt0 = (rg * 4 + wid) * 2;
  const int r0 = rt0 * 16;

  const f16* Abase = mS  + (size_t)rt0 * NKB * 512 + lane * 8;
  const f16* Bglob = WhS + (size_t)(colq * 4) * NKB * 512 + lane * 8;

  half8 Areg[2][8][2];
  f32x4 acc[2][4];
  #pragma unroll
  for (int a = 0; a < 2; a++)
    #pragma unroll
    for (int b = 0; b < 4; b++) { f32x4 z = {0.f, 0.f, 0.f, 0.f}; acc[a][b] = z; }

  // groups: 7 full (8 chunks) + tail (5 chunks) = 61
#define STAGE_B(g, buf, n_) { _Pragma("unroll") for (int q_ = 0; q_ < 8; q_++) { \
    int p_ = wid * 8 + q_; \
    if (p_ < (n_) * 4) { int kbl_ = p_ >> 2, gg_ = p_ & 3; \
      gll16(Bglob + ((size_t)gg_ * NKB + (g) * 8 + kbl_) * 512, &Bb[buf][kbl_][gg_][0]); } } }
#define LOADA_B(g, buf, n_) { _Pragma("unroll") for (int kk_ = 0; kk_ < 8; kk_++) if (kk_ < (n_)) { \
    Areg[buf][kk_][0] = *(const half8*)(Abase + (size_t)((g) * 8 + kk_) * 512); \
    Areg[buf][kk_][1] = *(const half8*)(Abase + ((size_t)NKB + (g) * 8 + kk_) * 512); } }
#define COMP_B(g, buf, n_) { _Pragma("unroll") for (int kk_ = 0; kk_ < 8; kk_++) if (kk_ < (n_)) { \
    half8 b0_ = *(const half8*)&Bb[buf][kk_][0][lane * 8]; \
    half8 b1_ = *(const half8*)&Bb[buf][kk_][1][lane * 8]; \
    half8 b2_ = *(const half8*)&Bb[buf][kk_][2][lane * 8]; \
    half8 b3_ = *(const half8*)&Bb[buf][kk_][3][lane * 8]; \
    _Pragma("unroll") for (int rf_ = 0; rf_ < 2; rf_++) { \
      acc[rf_][0] = __builtin_amdgcn_mfma_f32_16x16x32_f16(Areg[buf][kk_][rf_], b0_, acc[rf_][0], 0, 0, 0); \
      acc[rf_][1] = __builtin_amdgcn_mfma_f32_16x16x32_f16(Areg[buf][kk_][rf_], b1_, acc[rf_][1], 0, 0, 0); \
      acc[rf_][2] = __builtin_amdgcn_mfma_f32_16x16x32_f16(Areg[buf][kk_][rf_], b2_, acc[rf_][2], 0, 0, 0); \
      acc[rf_][3] = __builtin_amdgcn_mfma_f32_16x16x32_f16(Areg[buf][kk_][rf_], b3_, acc[rf_][3], 0, 0, 0); } } }

  LOADA_B(0, 0, 8); STAGE_B(0, 0, 8);
  __syncthreads();
  #pragma unroll
  for (int g = 0; g < 8; g++) {
    const int nn = (g == 7) ? 5 : 8;
    if (g < 7) {
      const int nn1 = (g == 6) ? 5 : 8;
      STAGE_B(g + 1, (g + 1) & 1, nn1); LOADA_B(g + 1, (g + 1) & 1, nn1);
    }
    COMP_B(g, g & 1, nn);
    __syncthreads();
  }
#undef STAGE_B
#undef LOADA_B
#undef COMP_B

  const int q4 = lane >> 4, c16 = lane & 15;
  const int j = colq * 16 + c16;
  const bool valid = j < H_;
  const int kbh = colq >> 1;
  const int lfh = ((((colq & 1) * 16 + c16) >> 3)) * 16;
  const int subh = c16 & 7;
  #pragma unroll
  for (int rf = 0; rf < 2; rf++) {
    f16* hdst = houtS + ((size_t)(rt0 + rf) * NKA + kbh) * 512 + subh;
    #pragma unroll
    for (int q = 0; q < 4; q++) {
      int rl = q4 * 4 + q;
      int row = r0 + rf * 16 + rl;
      if (valid) {
        size_t idx = (size_t)row * HP + j;
        float cold = c[idx];
        float iz = acc[rf][0][q], fz = acc[rf][1][q];
        float oz = acc[rf][2][q], uz = acc[rf][3][q];
        float cn = sigm(fz) * cold + sigm(iz) * tanh_(uz);
        float hv = sigm(oz) * tanh_(cn);
        c[idx] = cn;
        hdst[(rl + lfh) * 8] = (f16)hv;
        if (t == sel[row]) selH[idx] = hv;
      }
    }
  }
}

// ---------------- classifier ----------------

__global__ void k_xqS(const float* __restrict__ selH, const float* __restrict__ g1,
                      const float* __restrict__ be1, const float* __restrict__ mu1,
                      const float* __restrict__ var1, f16* __restrict__ xqS) {
  int i = blockIdx.x * 256 + threadIdx.x;
  if (i >= 256 * 3840) return;
  int k = i % 3840, s = i / 3840;
  float v = 0.f; bool have = false;
  if (k < H_)            { v = selH[(size_t)s * HP + k]; have = true; }
  else if (k < 2 * H_)   { v = selH[(size_t)(256 + s) * HP + (k - H_)]; have = true; }
  float q = 0.f;
  if (have) {
    float lr = v < 0.f ? 0.3f * v : v;
    q = (lr - mu1[k]) * rsqrtf(var1[k] + 1e-3f) * g1[k] + be1[k];
  }
  int rtile = s >> 4, sl = s & 15, kb = k >> 5, kl = k & 31;
  xqS[(((size_t)rtile * NKF + kb) * 512) + (sl + 16 * (kl >> 3)) * 8 + (kl & 7)] = (f16)q;
}

__global__ void k_w1S(const float* __restrict__ W1, f16* __restrict__ W1S) {
  int i = blockIdx.x * 256 + threadIdx.x;
  if (i >= 384 * 3840) return;
  int col = i % 384, k = i / 384;
  float v = (col < 380 && k < 2 * H_) ? W1[(size_t)k * 380 + col] : 0.f;
  int cg = col >> 4, nl = col & 15, kb = k >> 5, kl = k & 31;
  W1S[(((size_t)cg * NKF + kb) * 512) + (nl + 16 * (kl >> 3)) * 8 + (kl & 7)] = (f16)v;
}

// fc1: wave = 16 rows x 64 cols, K=3840 (120 chunks), branch-free pipeline
__global__ __launch_bounds__(256)
void k_fc1(const f16* __restrict__ xqS, const f16* __restrict__ W1S,
           const float* __restrict__ b1, float* __restrict__ z1) {
  const int lane = threadIdx.x & 63, wid = threadIdx.x >> 6;
  const int ct = blockIdx.x % 6, rg = blockIdx.x / 6;
  const int rtile = rg * 4 + wid;
  const int r0 = rtile * 16;

  const f16* Abase = xqS + (size_t)rtile * NKF * 512 + lane * 8;
  const f16* Bbase = W1S + (size_t)(ct * 4) * NKF * 512 + lane * 8;

  half8 fa0, fa1, fa2, fa3;
  half8 fb0[4], fb1[4], fb2[4], fb3[4];
  f32x4 acc[4];
  #pragma unroll
  for (int cb = 0; cb < 4; cb++) { f32x4 z = {0.f, 0.f, 0.f, 0.f}; acc[cb] = z; }

#define LDA_F(d, kb)  d = *(const half8*)(Abase + (size_t)(kb) * 512)
#define LDB_F(d, kb)  { _Pragma("unroll") for (int cb = 0; cb < 4; cb++) \
    d[cb] = *(const half8*)(Bbase + ((size_t)cb * NKF + (kb)) * 512); }
#define MMA_F(fa, fb) { _Pragma("unroll") for (int cb = 0; cb < 4; cb++) \
    acc[cb] = __builtin_amdgcn_mfma_f32_16x16x32_f16(fa, fb[cb], acc[cb], 0, 0, 0); }

  LDA_F(fa0, 0); LDB_F(fb0, 0);
  LDA_F(fa1, 1); LDB_F(fb1, 1);
  LDA_F(fa2, 2); LDB_F(fb2, 2);
  for (int base = 0; base < 116; base += 4) {
    LDA_F(fa3, base + 3); LDB_F(fb3, base + 3);
    MMA_F(fa0, fb0);
    LDA_F(fa0, base + 4); LDB_F(fb0, base + 4);
    MMA_F(fa1, fb1);
    LDA_F(fa1, base + 5); LDB_F(fb1, base + 5);
    MMA_F(fa2, fb2);
    LDA_F(fa2, base + 6); LDB_F(fb2, base + 6);
    MMA_F(fa3, fb3);
  }
  LDA_F(fa3, 119); LDB_F(fb3, 119);
  MMA_F(fa0, fb0);   // 116
  MMA_F(fa1, fb1);   // 117
  MMA_F(fa2, fb2);   // 118
  MMA_F(fa3, fb3);   // 119
#undef LDA_F
#undef LDB_F
#undef MMA_F

  const int q4 = lane >> 4, c16 = lane & 15;
  #pragma unroll
  for (int cb = 0; cb < 4; cb++)
    #pragma unroll
    for (int q = 0; q < 4; q++) {
      int row = r0 + q4 * 4 + q;
      int col = ct * 64 + cb * 16 + c16;
      float bias = (col < 380) ? b1[col] : 0.f;
      z1[(size_t)row * FCN + col] = acc[cb][q] + bias;
    }
}

__global__ void k_fc2(const float* __restrict__ z1, const float* __restrict__ g2,
                      const float* __restrict__ be2, const float* __restrict__ mu2,
                      const float* __restrict__ var2, const float* __restrict__ W2,
                      const float* __restrict__ b2, float* __restrict__ out) {
  int s = threadIdx.x;
  float a = 0.f;
  for (int jj = 0; jj < 380; jj++) {
    float v = z1[(size_t)s * FCN + jj];
    float lr = v < 0.f ? 0.3f * v : v;
    float q = (lr - mu2[jj]) * rsqrtf(var2[jj] + 1e-3f) * g2[jj] + be2[jj];
    a += q * W2[jj];
  }
  out[s] = a + b2[0];
}

// ---------------- host ----------------

extern "C" void kernel_launch(void* const* d_in, const int* in_sizes, int n_in,
                              void* d_out, int out_size, void* d_ws, size_t ws_size,
                              hipStream_t stream) {
  const int*   epix  = (const int*)d_in[0];
  const int*   lx    = (const int*)d_in[1];
  const int*   rx    = (const int*)d_in[2];
  const int*   totx  = (const int*)d_in[3];
  const float* embed = (const float*)d_in[4];
  const float* wx    = (const float*)d_in[5];
  const float* wh    = (const float*)d_in[6];
  const float* wmx   = (const float*)d_in[7];
  const float* wmh   = (const float*)d_in[8];
  const float* bb    = (const float*)d_in[9];
  const float* gx    = (const float*)d_in[10];
  const float* gh    = (const float*)d_in[11];
  const float* gmx   = (const float*)d_in[12];
  const float* gmh   = (const float*)d_in[13];
  const float* bn1g  = (const float*)d_in[14];
  const float* bn1b  = (const float*)d_in[15];
  const float* bn1m  = (const float*)d_in[16];
  const float* bn1v  = (const float*)d_in[17];
  const float* W1    = (const float*)d_in[18];
  const float* b1    = (const float*)d_in[19];
  const float* bn2g  = (const float*)d_in[20];
  const float* bn2b  = (const float*)d_in[21];
  const float* bn2m  = (const float*)d_in[22];
  const float* bn2v  = (const float*)d_in[23];
  const float* W2    = (const float*)d_in[24];
  const float* b2v   = (const float*)d_in[25];

  char* base = (char*)d_ws;
  size_t off = 0;
  auto alloc = [&](size_t n) { char* p = base + off; off = (off + n + 255) & ~(size_t)255; return p; };

  f16*   WmhS   = (f16*)  alloc((size_t)120 * NKA * 512 * 2);
  f16*   WhS    = (f16*)  alloc((size_t)119 * 4 * NKB * 512 * 2);
  f16*   wmxT   = (f16*)  alloc((size_t)HP * 32 * 2);
  f16*   xe16   = (f16*)  alloc((size_t)TT * NR * 32 * 2);
  f16*   h0S    = (f16*)  alloc((size_t)32 * NKA * 512 * 2);
  f16*   h1S    = (f16*)  alloc((size_t)32 * NKA * 512 * 2);
  f16*   mS     = (f16*)  alloc((size_t)32 * NKB * 512 * 2);
  float* cst    = (float*)alloc((size_t)NR * HP * 4);
  float* selH   = (float*)alloc((size_t)NR * HP * 4);
  int*   sel    = (int*)  alloc((size_t)NR * 4);
  float* inv_wh = (float*)alloc(7600 * 4);
  float* inv_wx = (float*)alloc(7600 * 4);
  float* inv_wmh= (float*)alloc(1900 * 4);
  float* inv_wmx= (float*)alloc(1900 * 4);
  float* npart  = (float*)alloc((size_t)4 * 19000 * 4);
  f16*   xqS    = (f16*)  alloc((size_t)16 * NKF * 512 * 2);
  f16*   W1S    = (f16*)  alloc((size_t)24 * NKF * 512 * 2);
  float* z1     = (float*)alloc((size_t)256 * FCN * 4);
  (void)in_sizes; (void)n_in; (void)out_size; (void)ws_size;

  hipLaunchKernelGGL(k_norms_p, dim3(300), dim3(256), 0, stream, wh, wx, wmh, wmx, npart);
  hipLaunchKernelGGL(k_norms_f, dim3(75), dim3(256), 0, stream,
                     npart, gh, gx, gmh, gmx, inv_wh, inv_wx, inv_wmh, inv_wmx);
  hipLaunchKernelGGL(k_wmhS, dim3((1920 * 1920 + 255) / 256), dim3(256), 0, stream,
                     wmh, inv_wmh, WmhS);
  hipLaunchKernelGGL(k_whS, dim3((7600 * 1952 + 255) / 256), dim3(256), 0, stream,
                     wh, wx, bb, inv_wh, inv_wx, WhS);
  hipLaunchKernelGGL(k_wmxT, dim3((HP * 32 + 255) / 256), dim3(256), 0, stream,
                     wmx, inv_wmx, wmxT);
  hipLaunchKernelGGL(k_lens, dim3(1), dim3(256), 0, stream, epix, lx, rx, sel);
  hipLaunchKernelGGL(k_init, dim3((NR * HP + 255) / 256), dim3(256), 0, stream,
                     h0S, h1S, cst);
  hipLaunchKernelGGL(k_xe16, dim3((TT * NR + 255) / 256), dim3(256), 0, stream,
                     totx, epix, embed, xe16);

  for (int t = 0; t < TT; t++) {
    int Mt = (t < TE) ? NR : 256;
    const f16* hin = (t & 1) ? h1S : h0S;
    f16*       ho  = (t & 1) ? h0S : h1S;
    int rgcA = Mt / 64;   // row-groups of 64 rows
    int rgcB = Mt / 128;  // row-groups of 128 rows
    // stepA grid: 8 (x) * rgcA * 2 (cbh) * 4 (chi) = 64*rgcA
    hipLaunchKernelGGL(k_stepA, dim3(64 * rgcA), dim3(256), 0, stream,
                       hin, WmhS, xe16 + (size_t)t * NR * 32, wmxT, mS, rgcA);
    hipLaunchKernelGGL(k_stepB, dim3(8 * rgcB * 15), dim3(256), 0, stream,
                       mS, WhS, cst, ho, selH, sel, t, rgcB);
  }

  hipLaunchKernelGGL(k_xqS, dim3((256 * 3840 + 255) / 256), dim3(256), 0, stream,
                     selH, bn1g, bn1b, bn1m, bn1v, xqS);
  hipLaunchKernelGGL(k_w1S, dim3((384 * 3840 + 255) / 256), dim3(256), 0, stream, W1, W1S);
  hipLaunchKernelGGL(k_fc1, dim3(24), dim3(256), 0, stream, xqS, W1S, b1, z1);
  hipLaunchKernelGGL(k_fc2, dim3(1), dim3(256), 0, stream,
                     z1, bn2g, bn2b, bn2m, bn2v, W2, b2v, (float*)d_out);
}

// Round 7
// 4308.490 us; speedup vs baseline: 1.7522x; 1.0894x over previous
//
#include <hip/hip_runtime.h>

// ---------------------------------------------------------------------------
// mLSTM epitope/antigen model, MI355X fp16-MFMA, round 13.
//
// R13 vs R12 (4.69 ms):
//  - stepB ROW-SPLIT + 2 BLOCKS/CU. R12 proved the recurrence is weight-
//    fill-CONCURRENCY bound (stepA split -> ~2x stepA). stepB (now ~2/3 of
//    step time, streams WhS 29.7 MB/step at ~1.6 TB/s) had 1 block/CU
//    (64 KB LDS). Now: wave = one 16-row rtile (was 2), block = 64 rows,
//    rgcB = Mt/64 -> 476/952 items; LDS 32 KB (2 buf x 4 chunks x 4 gates)
//    -> launch_bounds(256,2) -> 2 blocks/CU -> 2x in-flight misses.
//  - Traffic stays 1x beyond-L2: 4 row-blocks share each colq slice, all
//    mapped to the same XCD (blockIdx&7 == colq%8) -> L2 hits (the same
//    mechanism that kept R12's stepA split traffic-neutral).
//  - stepA, prep, classifier unchanged from R12.
// ---------------------------------------------------------------------------

typedef _Float16 f16;
typedef _Float16 half8 __attribute__((ext_vector_type(8)));
typedef float f32x4 __attribute__((ext_vector_type(4)));

#define H_    1900
#define HP    1920
#define NKA   60     // K-chunks for h/WmhS (1920/32)
#define NKB   61     // K-chunks for m/WhS (1952/32)
#define NKF   120    // K-chunks for fc1 (3840/32)
#define NR    512
#define TT    153
#define TE    25
#define EMB_  10
#define FCN   384

__device__ __forceinline__ float sigm(float x) {
  float p = __expf(-fabsf(x));
  float r = 1.f / (1.f + p);
  return x >= 0.f ? r : 1.f - r;
}
__device__ __forceinline__ float tanh_(float x) {
  float p = __expf(-2.f * fabsf(x));
  float r = (1.f - p) / (1.f + p);
  return x >= 0.f ? r : -r;
}

// async global->LDS, 16B per lane; LDS dest is wave-uniform base + lane*16
__device__ __forceinline__ void gll16(const f16* g, f16* l) {
  __builtin_amdgcn_global_load_lds(
      (const __attribute__((address_space(1))) unsigned int*)g,
      (__attribute__((address_space(3))) unsigned int*)l, 16, 0, 0);
}

// ---------------- prep ----------------

// 4-way K-split partial sums-of-squares (wh: K=1900=4x475; wx/wmx: seg 0 only)
__global__ void k_norms_p(const float* __restrict__ wh, const float* __restrict__ wx,
                          const float* __restrict__ wmh, const float* __restrict__ wmx,
                          float* __restrict__ part) {
  int seg = blockIdx.x & 3;
  int tid = (blockIdx.x >> 2) * 256 + threadIdx.x;   // 0..19199
  float s = 0.f;
  if (tid < 7600) {
    int k0 = seg * 475;
    for (int k = k0; k < k0 + 475; k++) { float v = wh[(size_t)k * 7600 + tid]; s += v * v; }
  } else if (tid < 15200) {
    if (seg == 0) {
      int n = tid - 7600;
      for (int e = 0; e < EMB_; e++) { float v = wx[(size_t)e * 7600 + n]; s += v * v; }
    }
  } else if (tid < 17100) {
    int n = tid - 15200; int k0 = seg * 475;
    for (int k = k0; k < k0 + 475; k++) { float v = wmh[(size_t)k * H_ + n]; s += v * v; }
  } else if (tid < 19000) {
    if (seg == 0) {
      int n = tid - 17100;
      for (int e = 0; e < EMB_; e++) { float v = wmx[(size_t)e * H_ + n]; s += v * v; }
    }
  }
  if (tid < 19000) part[(size_t)seg * 19000 + tid] = s;
}

__global__ void k_norms_f(const float* __restrict__ part,
                          const float* __restrict__ gh, const float* __restrict__ gx,
                          const float* __restrict__ gmh, const float* __restrict__ gmx,
                          float* __restrict__ inv_wh, float* __restrict__ inv_wx,
                          float* __restrict__ inv_wmh, float* __restrict__ inv_wmx) {
  int tid = blockIdx.x * 256 + threadIdx.x;
  if (tid >= 19000) return;
  float s = part[tid] + part[19000 + tid] + part[38000 + tid] + part[57000 + tid];
  float r = rsqrtf(fmaxf(s, 1e-12f));
  if (tid < 7600)        inv_wh[tid] = gh[tid] * r;
  else if (tid < 15200)  { int n = tid - 7600;  inv_wx[n]  = gx[n]  * r; }
  else if (tid < 17100)  { int n = tid - 15200; inv_wmh[n] = gmh[n] * r; }
  else                   { int n = tid - 17100; inv_wmx[n] = gmx[n] * r; }
}

// WmhS fragment-swizzled: group (c,kb): element (n=16c+nl, k=32kb+kl)
__global__ void k_wmhS(const float* __restrict__ wmh, const float* __restrict__ inv,
                       f16* __restrict__ WmhS) {
  int i = blockIdx.x * 256 + threadIdx.x;
  if (i >= 1920 * 1920) return;
  int n = i % 1920, k = i / 1920;
  float v = (n < H_ && k < H_) ? wmh[(size_t)k * H_ + n] * inv[n] : 0.f;
  int c = n >> 4, nl = n & 15, kb = k >> 5, kl = k & 31;
  WmhS[(((size_t)c * NKA + kb) * 512) + (nl + 16 * (kl >> 3)) * 8 + (kl & 7)] = (f16)v;
}

// WhS fragment-swizzled, gate-grouped: group (q*4+g, kb); K-ext rows carry wx/b
__global__ void k_whS(const float* __restrict__ wh, const float* __restrict__ wx,
                      const float* __restrict__ bias,
                      const float* __restrict__ inv_wh, const float* __restrict__ inv_wx,
                      f16* __restrict__ WhS) {
  int i = blockIdx.x * 256 + threadIdx.x;
  if (i >= 7600 * 1952) return;
  int col = i % 7600, k = i / 7600;
  float v = 0.f;
  if (k < H_)                        v = wh[(size_t)k * 7600 + col] * inv_wh[col];
  else if (k >= HP && k < HP + EMB_) v = wx[(size_t)(k - HP) * 7600 + col] * inv_wx[col];
  else if (k == HP + EMB_)           v = bias[col];
  int g = col / H_, n = col % H_;
  int q = n >> 4, nl = n & 15, kb = k >> 5, kl = k & 31;
  WhS[(((size_t)(q * 4 + g) * NKB + kb) * 512) + (nl + 16 * (kl >> 3)) * 8 + (kl & 7)] = (f16)v;
}

__global__ void k_wmxT(const float* __restrict__ wmx, const float* __restrict__ inv_wmx,
                       f16* __restrict__ wmxT) {
  int i = blockIdx.x * 256 + threadIdx.x;
  if (i >= HP * 32) return;
  int n = i >> 5, k = i & 31;
  float v = (k < EMB_ && n < H_) ? wmx[(size_t)k * H_ + n] * inv_wmx[n] : 0.f;
  wmxT[i] = (f16)v;
}

__global__ void k_lens(const int* __restrict__ ex, const int* __restrict__ lx,
                       const int* __restrict__ rx, int* __restrict__ sel) {
  int s = threadIdx.x;
  int el = 0; for (int i = 0; i < 25; i++) el += (ex[s * 25 + i] != 26);
  int ll = 0; for (int i = 0; i < 64; i++) ll += (lx[s * 64 + i] != 26);
  int rl = 0; for (int i = 0; i < 64; i++) rl += (rx[s * 64 + i] != 26);
  ll = ll < 1 ? 1 : ll;  rl = rl < 1 ? 1 : rl;
  int tl = el + ll + rl;
  int ti = tl - 1; ti = ti < 0 ? 0 : (ti > 152 ? 152 : ti);
  int ei = el - 1; ei = ei < 0 ? 0 : (ei > 24 ? 24 : ei);
  sel[s] = ti; sel[256 + s] = ei;
}

__global__ void k_init(f16* __restrict__ h0, f16* __restrict__ h1, float* __restrict__ c) {
  int i = blockIdx.x * 256 + threadIdx.x;
  if (i < NR * HP) { h0[i] = (f16)0.f; h1[i] = (f16)0.f; c[i] = 0.f; }
}

// xe16[t][row][32]: cols 0..9 = embed[token], col 10 = 1.0 (bias), rest 0
__global__ void k_xe16(const int* __restrict__ totx, const int* __restrict__ epix,
                       const float* __restrict__ embed, f16* __restrict__ xe16) {
  int i = blockIdx.x * blockDim.x + threadIdx.x;
  if (i >= TT * NR) return;
  int t = i / NR, r = i % NR;
  int tok = -1;
  if (r < 256) tok = totx[r * TT + t];
  else if (t < TE) tok = epix[(r - 256) * TE + t];
  f16* o = xe16 + (size_t)i * 32;
  #pragma unroll
  for (int e = 0; e < EMB_; e++) o[e] = (f16)(tok >= 0 ? embed[tok * EMB_ + e] : 0.f);
  o[10] = (f16)1.f;
  #pragma unroll
  for (int e = 11; e < 32; e++) o[e] = (f16)0.f;
}

// ---------------- recurrence ----------------

// Phase A: block = (ct, cbh, rg); 4 waves x 16 rows x 32 cols (2 cb).
// B (WmhS half-slice) staged in LDS (32 KB, double-buffered), A in regs
// one group ahead. 2 blocks/CU. (R12 body, unchanged.)
__global__ __launch_bounds__(256, 2)
void k_stepA(const f16* __restrict__ hS, const f16* __restrict__ WmhS,
             const f16* __restrict__ xe16_t, const f16* __restrict__ wmxT,
             f16* __restrict__ mS, int rgc) {
  __shared__ __align__(16) f16 Bb[2][8][2][512];   // 32 KB
  const int lane = threadIdx.x & 63, wid = threadIdx.x >> 6;
  const int bi = blockIdx.x;
  const int x = bi & 7, mm = bi >> 3;
  const int rg = mm % rgc, rem = mm / rgc;
  const int cbh = rem & 1, chi = rem >> 1;
  const int ct = chi * 8 + x;                      // ct%8 == x (XCD-stable)
  if (ct >= 30) return;
  const int rtile = rg * 4 + wid;
  const int r0 = rtile * 16;
  const int l16 = lane & 15, l4 = lane >> 4;

  const f16* Abase = hS   + (size_t)rtile * NKA * 512 + lane * 8;
  const f16* Bglob = WmhS + (size_t)(ct * 4 + cbh * 2) * NKA * 512 + lane * 8;

  // xm = xe16 @ wmxT (once per wave, this block's 2 column-16-groups)
  f32x4 xm[2];
  {
    half8 xa = *(const half8*)(xe16_t + (size_t)(r0 + l16) * 32 + l4 * 8);
    #pragma unroll
    for (int cb = 0; cb < 2; cb++) {
      half8 xb = *(const half8*)(wmxT + (size_t)(ct * 64 + (cbh * 2 + cb) * 16 + l16) * 32 + l4 * 8);
      f32x4 z = {0.f, 0.f, 0.f, 0.f};
      xm[cb] = __builtin_amdgcn_mfma_f32_16x16x32_f16(xa, xb, z, 0, 0, 0);
    }
  }

  half8 Areg[2][8];
  f32x4 acc[2];
  #pragma unroll
  for (int cb = 0; cb < 2; cb++) { f32x4 z = {0.f, 0.f, 0.f, 0.f}; acc[cb] = z; }

#define STAGE_A(g, buf, n_) { _Pragma("unroll") for (int q_ = 0; q_ < ((n_) >> 1); q_++) { \
    int p_ = wid * ((n_) >> 1) + q_; int kbl_ = p_ >> 1, cb_ = p_ & 1; \
    gll16(Bglob + ((size_t)cb_ * NKA + (g) * 8 + kbl_) * 512, &Bb[buf][kbl_][cb_][0]); } }
#define LOADA_A(g, buf, n_) { _Pragma("unroll") for (int kk_ = 0; kk_ < 8; kk_++) if (kk_ < (n_)) \
    Areg[buf][kk_] = *(const half8*)(Abase + (size_t)((g) * 8 + kk_) * 512); }
#define COMP_A(g, buf, n_) { _Pragma("unroll") for (int kk_ = 0; kk_ < 8; kk_++) if (kk_ < (n_)) { \
    half8 b0_ = *(const half8*)&Bb[buf][kk_][0][lane * 8]; \
    half8 b1_ = *(const half8*)&Bb[buf][kk_][1][lane * 8]; \
    acc[0] = __builtin_amdgcn_mfma_f32_16x16x32_f16(Areg[buf][kk_], b0_, acc[0], 0, 0, 0); \
    acc[1] = __builtin_amdgcn_mfma_f32_16x16x32_f16(Areg[buf][kk_], b1_, acc[1], 0, 0, 0); } }

  LOADA_A(0, 0, 8); STAGE_A(0, 0, 8);
  __syncthreads();
  #pragma unroll
  for (int g = 0; g < 8; g++) {
    const int nn = (g == 7) ? 4 : 8;
    if (g < 7) {
      const int nn1 = (g == 6) ? 4 : 8;
      STAGE_A(g + 1, (g + 1) & 1, nn1); LOADA_A(g + 1, (g + 1) & 1, nn1);
    }
    COMP_A(g, g & 1, nn);
    __syncthreads();
  }
#undef STAGE_A
#undef LOADA_A
#undef COMP_A

  // epilogue: m = hm * xm, written in stepB's A-fragment order.
  const int q4 = lane >> 4, c16 = lane & 15;
  const int kb = ct * 2 + cbh;
  #pragma unroll
  for (int cb = 0; cb < 2; cb++) {
    int klane = cb * 16 + c16;
    int lf = (klane >> 3) * 16;
    int sub = c16 & 7;
    f16* dst = mS + ((size_t)rtile * NKB + kb) * 512 + sub;
    #pragma unroll
    for (int q = 0; q < 4; q++) {
      int rl = q4 * 4 + q;
      dst[(rl + lf) * 8] = (f16)(acc[cb][q] * xm[cb][q]);
    }
  }
  if (ct == 0 && cbh == 0) {  // K-extension chunk 60 = xe16 row (contiguous copy)
    f16* dst = mS + ((size_t)rtile * NKB + 60) * 512 + lane * 8;
    *(half8*)dst = *(const half8*)(xe16_t + (size_t)(r0 + l16) * 32 + l4 * 8);
  }
}

// Phase B: block = (colq, rg); 4 waves x ONE 16-row rtile each (64 rows/block).
// B (WhS gate-quad) staged in LDS 32 KB (2 buf x 4 chunks x 4 gates) ->
// 2 blocks/CU. A (mS rows) per-wave registers one group ahead.
// Groups: 15 full (4 chunks) + tail (1 chunk) = 61.
__global__ __launch_bounds__(256, 2)
void k_stepB(const f16* __restrict__ mS, const f16* __restrict__ WhS,
             float* __restrict__ c, f16* __restrict__ houtS,
             float* __restrict__ selH, const int* __restrict__ sel, int t, int rgc) {
  __shared__ __align__(16) f16 Bb[2][4][4][512];   // 32 KB
  const int lane = threadIdx.x & 63, wid = threadIdx.x >> 6;
  const int bi = blockIdx.x;
  const int x = bi & 7, mm = bi >> 3;
  const int rg = mm % rgc, chi = mm / rgc;
  const int colq = chi * 8 + x;                    // colq%8 == x (XCD-stable)
  if (colq >= 119) return;
  const int rtile = rg * 4 + wid;
  const int r0 = rtile * 16;

  const f16* Abase = mS  + (size_t)rtile * NKB * 512 + lane * 8;
  const f16* Bglob = WhS + (size_t)(colq * 4) * NKB * 512 + lane * 8;

  half8 Areg[2][4];
  f32x4 acc[4];
  #pragma unroll
  for (int b = 0; b < 4; b++) { f32x4 z = {0.f, 0.f, 0.f, 0.f}; acc[b] = z; }

  // stage group g (n_ chunks): n_*4 fragments, n_ per wave.
  // n_=4: p_=wid*4+q_ -> kbl_=wid, gg_=q_.  n_=1: p_=wid -> kbl_=0, gg_=wid.
#define STAGE_B(g, buf, n_) { _Pragma("unroll") for (int q_ = 0; q_ < (n_); q_++) { \
    int p_ = wid * (n_) + q_; int kbl_ = p_ >> 2, gg_ = p_ & 3; \
    gll16(Bglob + ((size_t)gg_ * NKB + (g) * 4 + kbl_) * 512, &Bb[buf][kbl_][gg_][0]); } }
#define LOADA_B(g, buf, n_) { _Pragma("unroll") for (int kk_ = 0; kk_ < 4; kk_++) if (kk_ < (n_)) \
    Areg[buf][kk_] = *(const half8*)(Abase + (size_t)((g) * 4 + kk_) * 512); }
#define COMP_B(g, buf, n_) { _Pragma("unroll") for (int kk_ = 0; kk_ < 4; kk_++) if (kk_ < (n_)) { \
    half8 b0_ = *(const half8*)&Bb[buf][kk_][0][lane * 8]; \
    half8 b1_ = *(const half8*)&Bb[buf][kk_][1][lane * 8]; \
    half8 b2_ = *(const half8*)&Bb[buf][kk_][2][lane * 8]; \
    half8 b3_ = *(const half8*)&Bb[buf][kk_][3][lane * 8]; \
    acc[0] = __builtin_amdgcn_mfma_f32_16x16x32_f16(Areg[buf][kk_], b0_, acc[0], 0, 0, 0); \
    acc[1] = __builtin_amdgcn_mfma_f32_16x16x32_f16(Areg[buf][kk_], b1_, acc[1], 0, 0, 0); \
    acc[2] = __builtin_amdgcn_mfma_f32_16x16x32_f16(Areg[buf][kk_], b2_, acc[2], 0, 0, 0); \
    acc[3] = __builtin_amdgcn_mfma_f32_16x16x32_f16(Areg[buf][kk_], b3_, acc[3], 0, 0, 0); } }

  LOADA_B(0, 0, 4); STAGE_B(0, 0, 4);
  __syncthreads();
  #pragma unroll
  for (int g = 0; g < 16; g++) {
    const int nn = (g == 15) ? 1 : 4;
    if (g < 15) {
      const int nn1 = (g == 14) ? 1 : 4;
      STAGE_B(g + 1, (g + 1) & 1, nn1); LOADA_B(g + 1, (g + 1) & 1, nn1);
    }
    COMP_B(g, g & 1, nn);
    __syncthreads();
  }
#undef STAGE_B
#undef LOADA_B
#undef COMP_B

  const int q4 = lane >> 4, c16 = lane & 15;
  const int j = colq * 16 + c16;
  const bool valid = j < H_;
  const int kbh = colq >> 1;
  const int lfh = ((((colq & 1) * 16 + c16) >> 3)) * 16;
  const int subh = c16 & 7;
  f16* hdst = houtS + ((size_t)rtile * NKA + kbh) * 512 + subh;
  #pragma unroll
  for (int q = 0; q < 4; q++) {
    int rl = q4 * 4 + q;
    int row = r0 + rl;
    if (valid) {
      size_t idx = (size_t)row * HP + j;
      float cold = c[idx];
      float iz = acc[0][q], fz = acc[1][q];
      float oz = acc[2][q], uz = acc[3][q];
      float cn = sigm(fz) * cold + sigm(iz) * tanh_(uz);
      float hv = sigm(oz) * tanh_(cn);
      c[idx] = cn;
      hdst[(rl + lfh) * 8] = (f16)hv;
      if (t == sel[row]) selH[idx] = hv;
    }
  }
}

// ---------------- classifier ----------------

__global__ void k_xqS(const float* __restrict__ selH, const float* __restrict__ g1,
                      const float* __restrict__ be1, const float* __restrict__ mu1,
                      const float* __restrict__ var1, f16* __restrict__ xqS) {
  int i = blockIdx.x * 256 + threadIdx.x;
  if (i >= 256 * 3840) return;
  int k = i % 3840, s = i / 3840;
  float v = 0.f; bool have = false;
  if (k < H_)            { v = selH[(size_t)s * HP + k]; have = true; }
  else if (k < 2 * H_)   { v = selH[(size_t)(256 + s) * HP + (k - H_)]; have = true; }
  float q = 0.f;
  if (have) {
    float lr = v < 0.f ? 0.3f * v : v;
    q = (lr - mu1[k]) * rsqrtf(var1[k] + 1e-3f) * g1[k] + be1[k];
  }
  int rtile = s >> 4, sl = s & 15, kb = k >> 5, kl = k & 31;
  xqS[(((size_t)rtile * NKF + kb) * 512) + (sl + 16 * (kl >> 3)) * 8 + (kl & 7)] = (f16)q;
}

__global__ void k_w1S(const float* __restrict__ W1, f16* __restrict__ W1S) {
  int i = blockIdx.x * 256 + threadIdx.x;
  if (i >= 384 * 3840) return;
  int col = i % 384, k = i / 384;
  float v = (col < 380 && k < 2 * H_) ? W1[(size_t)k * 380 + col] : 0.f;
  int cg = col >> 4, nl = col & 15, kb = k >> 5, kl = k & 31;
  W1S[(((size_t)cg * NKF + kb) * 512) + (nl + 16 * (kl >> 3)) * 8 + (kl & 7)] = (f16)v;
}

// fc1: wave = 16 rows x 64 cols, K=3840 (120 chunks), branch-free pipeline
__global__ __launch_bounds__(256)
void k_fc1(const f16* __restrict__ xqS, const f16* __restrict__ W1S,
           const float* __restrict__ b1, float* __restrict__ z1) {
  const int lane = threadIdx.x & 63, wid = threadIdx.x >> 6;
  const int ct = blockIdx.x % 6, rg = blockIdx.x / 6;
  const int rtile = rg * 4 + wid;
  const int r0 = rtile * 16;

  const f16* Abase = xqS + (size_t)rtile * NKF * 512 + lane * 8;
  const f16* Bbase = W1S + (size_t)(ct * 4) * NKF * 512 + lane * 8;

  half8 fa0, fa1, fa2, fa3;
  half8 fb0[4], fb1[4], fb2[4], fb3[4];
  f32x4 acc[4];
  #pragma unroll
  for (int cb = 0; cb < 4; cb++) { f32x4 z = {0.f, 0.f, 0.f, 0.f}; acc[cb] = z; }

#define LDA_F(d, kb)  d = *(const half8*)(Abase + (size_t)(kb) * 512)
#define LDB_F(d, kb)  { _Pragma("unroll") for (int cb = 0; cb < 4; cb++) \
    d[cb] = *(const half8*)(Bbase + ((size_t)cb * NKF + (kb)) * 512); }
#define MMA_F(fa, fb) { _Pragma("unroll") for (int cb = 0; cb < 4; cb++) \
    acc[cb] = __builtin_amdgcn_mfma_f32_16x16x32_f16(fa, fb[cb], acc[cb], 0, 0, 0); }

  LDA_F(fa0, 0); LDB_F(fb0, 0);
  LDA_F(fa1, 1); LDB_F(fb1, 1);
  LDA_F(fa2, 2); LDB_F(fb2, 2);
  for (int base = 0; base < 116; base += 4) {
    LDA_F(fa3, base + 3); LDB_F(fb3, base + 3);
    MMA_F(fa0, fb0);
    LDA_F(fa0, base + 4); LDB_F(fb0, base + 4);
    MMA_F(fa1, fb1);
    LDA_F(fa1, base + 5); LDB_F(fb1, base + 5);
    MMA_F(fa2, fb2);
    LDA_F(fa2, base + 6); LDB_F(fb2, base + 6);
    MMA_F(fa3, fb3);
  }
  LDA_F(fa3, 119); LDB_F(fb3, 119);
  MMA_F(fa0, fb0);   // 116
  MMA_F(fa1, fb1);   // 117
  MMA_F(fa2, fb2);   // 118
  MMA_F(fa3, fb3);   // 119
#undef LDA_F
#undef LDB_F
#undef MMA_F

  const int q4 = lane >> 4, c16 = lane & 15;
  #pragma unroll
  for (int cb = 0; cb < 4; cb++)
    #pragma unroll
    for (int q = 0; q < 4; q++) {
      int row = r0 + q4 * 4 + q;
      int col = ct * 64 + cb * 16 + c16;
      float bias = (col < 380) ? b1[col] : 0.f;
      z1[(size_t)row * FCN + col] = acc[cb][q] + bias;
    }
}

__global__ void k_fc2(const float* __restrict__ z1, const float* __restrict__ g2,
                      const float* __restrict__ be2, const float* __restrict__ mu2,
                      const float* __restrict__ var2, const float* __restrict__ W2,
                      const float* __restrict__ b2, float* __restrict__ out) {
  int s = threadIdx.x;
  float a = 0.f;
  for (int jj = 0; jj < 380; jj++) {
    float v = z1[(size_t)s * FCN + jj];
    float lr = v < 0.f ? 0.3f * v : v;
    float q = (lr - mu2[jj]) * rsqrtf(var2[jj] + 1e-3f) * g2[jj] + be2[jj];
    a += q * W2[jj];
  }
  out[s] = a + b2[0];
}

// ---------------- host ----------------

extern "C" void kernel_launch(void* const* d_in, const int* in_sizes, int n_in,
                              void* d_out, int out_size, void* d_ws, size_t ws_size,
                              hipStream_t stream) {
  const int*   epix  = (const int*)d_in[0];
  const int*   lx    = (const int*)d_in[1];
  const int*   rx    = (const int*)d_in[2];
  const int*   totx  = (const int*)d_in[3];
  const float* embed = (const float*)d_in[4];
  const float* wx    = (const float*)d_in[5];
  const float* wh    = (const float*)d_in[6];
  const float* wmx   = (const float*)d_in[7];
  const float* wmh   = (const float*)d_in[8];
  const float* bb    = (const float*)d_in[9];
  const float* gx    = (const float*)d_in[10];
  const float* gh    = (const float*)d_in[11];
  const float* gmx   = (const float*)d_in[12];
  const float* gmh   = (const float*)d_in[13];
  const float* bn1g  = (const float*)d_in[14];
  const float* bn1b  = (const float*)d_in[15];
  const float* bn1m  = (const float*)d_in[16];
  const float* bn1v  = (const float*)d_in[17];
  const float* W1    = (const float*)d_in[18];
  const float* b1    = (const float*)d_in[19];
  const float* bn2g  = (const float*)d_in[20];
  const float* bn2b  = (const float*)d_in[21];
  const float* bn2m  = (const float*)d_in[22];
  const float* bn2v  = (const float*)d_in[23];
  const float* W2    = (const float*)d_in[24];
  const float* b2v   = (const float*)d_in[25];

  char* base = (char*)d_ws;
  size_t off = 0;
  auto alloc = [&](size_t n) { char* p = base + off; off = (off + n + 255) & ~(size_t)255; return p; };

  f16*   WmhS   = (f16*)  alloc((size_t)120 * NKA * 512 * 2);
  f16*   WhS    = (f16*)  alloc((size_t)119 * 4 * NKB * 512 * 2);
  f16*   wmxT   = (f16*)  alloc((size_t)HP * 32 * 2);
  f16*   xe16   = (f16*)  alloc((size_t)TT * NR * 32 * 2);
  f16*   h0S    = (f16*)  alloc((size_t)32 * NKA * 512 * 2);
  f16*   h1S    = (f16*)  alloc((size_t)32 * NKA * 512 * 2);
  f16*   mS     = (f16*)  alloc((size_t)32 * NKB * 512 * 2);
  float* cst    = (float*)alloc((size_t)NR * HP * 4);
  float* selH   = (float*)alloc((size_t)NR * HP * 4);
  int*   sel    = (int*)  alloc((size_t)NR * 4);
  float* inv_wh = (float*)alloc(7600 * 4);
  float* inv_wx = (float*)alloc(7600 * 4);
  float* inv_wmh= (float*)alloc(1900 * 4);
  float* inv_wmx= (float*)alloc(1900 * 4);
  float* npart  = (float*)alloc((size_t)4 * 19000 * 4);
  f16*   xqS    = (f16*)  alloc((size_t)16 * NKF * 512 * 2);
  f16*   W1S    = (f16*)  alloc((size_t)24 * NKF * 512 * 2);
  float* z1     = (float*)alloc((size_t)256 * FCN * 4);
  (void)in_sizes; (void)n_in; (void)out_size; (void)ws_size;

  hipLaunchKernelGGL(k_norms_p, dim3(300), dim3(256), 0, stream, wh, wx, wmh, wmx, npart);
  hipLaunchKernelGGL(k_norms_f, dim3(75), dim3(256), 0, stream,
                     npart, gh, gx, gmh, gmx, inv_wh, inv_wx, inv_wmh, inv_wmx);
  hipLaunchKernelGGL(k_wmhS, dim3((1920 * 1920 + 255) / 256), dim3(256), 0, stream,
                     wmh, inv_wmh, WmhS);
  hipLaunchKernelGGL(k_whS, dim3((7600 * 1952 + 255) / 256), dim3(256), 0, stream,
                     wh, wx, bb, inv_wh, inv_wx, WhS);
  hipLaunchKernelGGL(k_wmxT, dim3((HP * 32 + 255) / 256), dim3(256), 0, stream,
                     wmx, inv_wmx, wmxT);
  hipLaunchKernelGGL(k_lens, dim3(1), dim3(256), 0, stream, epix, lx, rx, sel);
  hipLaunchKernelGGL(k_init, dim3((NR * HP + 255) / 256), dim3(256), 0, stream,
                     h0S, h1S, cst);
  hipLaunchKernelGGL(k_xe16, dim3((TT * NR + 255) / 256), dim3(256), 0, stream,
                     totx, epix, embed, xe16);

  for (int t = 0; t < TT; t++) {
    int Mt = (t < TE) ? NR : 256;
    const f16* hin = (t & 1) ? h1S : h0S;
    f16*       ho  = (t & 1) ? h0S : h1S;
    int rgcA = Mt / 64;   // stepA row-groups of 64 rows
    int rgcB = Mt / 64;   // stepB row-groups of 64 rows (was 128)
    hipLaunchKernelGGL(k_stepA, dim3(64 * rgcA), dim3(256), 0, stream,
                       hin, WmhS, xe16 + (size_t)t * NR * 32, wmxT, mS, rgcA);
    hipLaunchKernelGGL(k_stepB, dim3(8 * rgcB * 15), dim3(256), 0, stream,
                       mS, WhS, cst, ho, selH, sel, t, rgcB);
  }

  hipLaunchKernelGGL(k_xqS, dim3((256 * 3840 + 255) / 256), dim3(256), 0, stream,
                     selH, bn1g, bn1b, bn1m, bn1v, xqS);
  hipLaunchKernelGGL(k_w1S, dim3((384 * 3840 + 255) / 256), dim3(256), 0, stream, W1, W1S);
  hipLaunchKernelGGL(k_fc1, dim3(24), dim3(256), 0, stream, xqS, W1S, b1, z1);
  hipLaunchKernelGGL(k_fc2, dim3(1), dim3(256), 0, stream,
                     z1, bn2g, bn2b, bn2m, bn2v, W2, b2v, (float*)d_out);
}